// Round 1
// baseline (957.314 us; speedup 1.0000x reference)
//
#include <hip/hip_runtime.h>

#define NF 2097152   // 4*32*128*128 elements per [B,K,H,W] array

// ---------------------------------------------------------------------------
// DP kernel: computes left/right logsumexp scans for both orientations.
//   blocks 0..127    : vertical chains  (scan over h; w contiguous -> streamed)
//   blocks 128..1151 : horizontal chains (scan over w; LDS-staged, coalesced)
// left_h -> d_out slot2, left_v -> d_out slot3 (overwritten by combine),
// right_h -> ws, right_v -> ws+NF.
// ---------------------------------------------------------------------------
__global__ __launch_bounds__(256) void dp_kernel(
    const float* __restrict__ hu, const float* __restrict__ vu,
    const float* __restrict__ hp, const float* __restrict__ vp,
    const float* __restrict__ gam,
    float* __restrict__ lh, float* __restrict__ rh,
    float* __restrict__ lv, float* __restrict__ rv)
{
    __shared__ float smem[16976];   // H: pbuf[16][1025]+cc[2*32]+rmx[256]+rs[256]; V: cb[2][32][8]
    const float g  = gam[0];
    const float ig = 1.0f / g;
    const int tid = threadIdx.x;
    const int blk = blockIdx.x;

    if (blk < 128) {
        // ----------------- VERTICAL: thread = (state k, chain w) -----------------
        const int dir  = blk & 1;
        const int b    = (blk >> 1) & 3;
        const int rblk = blk >> 3;                 // 0..15
        const int rl   = tid & 7;
        const int r    = rblk * 8 + rl;            // chain index w
        const int k    = tid >> 3;                 // state 0..31
        float* cb = smem;                          // [2][32*8]

        // p[b,j,k,hh,w]: j stride 520192, k stride 16256, hh stride 128, w stride 1
        const int sIt  = dir ? 16256  : 520192;    // iterated state slot
        const int sFix = dir ? 520192 : 16256;     // this thread's state slot
        const int pbase = b * 16646144 + k * sFix + r;
        const int ubase = (b * 32 + k) * 16384 + r;
        const float* __restrict__ p = vp;
        const float* __restrict__ u = vu;
        float* __restrict__ out = dir ? rv : lv;

        const int pos0 = dir ? 127 : 0;
        const float c0 = u[ubase + pos0 * 128];
        cb[k * 8 + rl] = c0;
        out[ubase + pos0 * 128] = c0;

        float pv[32], pn[32];
        {
            const int pp1 = dir ? 126 : 0;         // pairwise pos for step 1
            const int ib = pbase + pp1 * 128;
            #pragma unroll
            for (int j = 0; j < 32; ++j) pv[j] = p[ib + j * sIt];
        }
        float un  = u[ubase + (dir ? 126 : 1) * 128];
        float un2 = 0.0f;
        __syncthreads();

        for (int s = 1; s < 128; ++s) {
            const int pos = dir ? 127 - s : s;
            if (s < 127) {                         // prefetch step s+1
                const int npp = dir ? 126 - s : s;
                const int ib = pbase + npp * 128;
                #pragma unroll
                for (int j = 0; j < 32; ++j) pn[j] = p[ib + j * sIt];
                un2 = u[ubase + (dir ? 126 - s : s + 1) * 128];
            }
            const float* cs = cb + (((s + 1) & 1) << 8);
            float mx = -3.4e38f;
            #pragma unroll
            for (int j = 0; j < 32; ++j) {
                const float v = pv[j] + cs[j * 8 + rl];
                pv[j] = v;
                mx = fmaxf(mx, v);
            }
            float ss = 0.0f;
            #pragma unroll
            for (int j = 0; j < 32; ++j) ss += __expf((pv[j] - mx) * ig);
            const float nv = un + mx + g * __logf(ss);
            out[ubase + pos * 128] = nv;
            cb[((s & 1) << 8) + k * 8 + rl] = nv;
            un = un2;
            #pragma unroll
            for (int j = 0; j < 32; ++j) pv[j] = pn[j];
            __syncthreads();
        }
    } else {
        // ----------------- HORIZONTAL: one block per chain (b,h,dir) -----------------
        const int hid = blk - 128;                 // 0..1023
        const int dir = hid & 1;
        const int b   = (hid >> 1) & 3;
        const int h   = hid >> 3;                  // 0..127
        float (* __restrict__ pbuf)[1025] = (float(*)[1025])smem;
        float* cc  = smem + 16400;                 // [2][32]
        float* rmx = smem + 16464;                 // [8][32]
        float* rs  = smem + 16720;                 // [8][32]
        const float* __restrict__ p = hp;
        const float* __restrict__ u = hu;
        float* __restrict__ out = dir ? rh : lh;
        // p[b,j,k,h,l]: jk stride 16256, h stride 127, l stride 1
        const int pb = b * 16646144 + h * 127;
        const int ub = b * 524288 + h * 128;       // + k*16384 + pos
        const int pos0 = dir ? 127 : 0;
        if (tid < 32) {
            const float c0 = u[ub + tid * 16384 + pos0];
            cc[tid] = c0;
            out[ub + tid * 16384 + pos0] = c0;
        }
        const int k  = tid & 31;
        const int jq = tid >> 5;
        int sc = 0;
        for (int ci = 0; ci < 8; ++ci) {
            const int l0 = dir ? 112 - ci * 16 : ci * 16;
            const int nl = (l0 == 112) ? 15 : 16;
            __syncthreads();
            // stage p[:, :, h, l0:l0+nl] -> LDS; coalesced 64B runs along l
            #pragma unroll 8
            for (int i = 0; i < 64; ++i) {
                const int q  = i * 256 + tid;
                const int jk = q >> 4, lo = q & 15;
                if (lo < nl) {
                    const float v = p[pb + jk * 16256 + l0 + lo];
                    // bwd: store transposed so reads are pbuf[lo][j*32+k] in both dirs
                    const int col = dir ? (((jk & 31) << 5) | (jk >> 5)) : jk;
                    pbuf[lo][col] = v;
                }
            }
            __syncthreads();
            for (int li = 0; li < nl; ++li) {
                const int lo  = dir ? nl - 1 - li : li;
                const int pos = dir ? l0 + lo : l0 + lo + 1;
                const float* cs = cc + ((sc & 1) << 5);
                float vals[4];
                float pm = -3.4e38f;
                #pragma unroll
                for (int jj = 0; jj < 4; ++jj) {
                    const int j = jq * 4 + jj;
                    const float v = pbuf[lo][j * 32 + k] + cs[j];
                    vals[jj] = v;
                    pm = fmaxf(pm, v);
                }
                float ps = 0.0f;
                #pragma unroll
                for (int jj = 0; jj < 4; ++jj) ps += __expf((vals[jj] - pm) * ig);
                rmx[jq * 32 + k] = pm;
                rs [jq * 32 + k] = ps;
                __syncthreads();
                if (tid < 32) {
                    float mx = rmx[tid];
                    #pragma unroll
                    for (int q2 = 1; q2 < 8; ++q2) mx = fmaxf(mx, rmx[q2 * 32 + tid]);
                    float ssum = 0.0f;
                    #pragma unroll
                    for (int q2 = 0; q2 < 8; ++q2)
                        ssum += rs[q2 * 32 + tid] * __expf((rmx[q2 * 32 + tid] - mx) * ig);
                    const float m  = mx + g * __logf(ssum);
                    const float nv = u[ub + tid * 16384 + pos] + m;
                    out[ub + tid * 16384 + pos] = nv;
                    cc[(((sc + 1) & 1) << 5) + tid] = nv;
                }
                __syncthreads();
                ++sc;
            }
        }
    }
}

// ---------------------------------------------------------------------------
// Combine: marg = left + right - u; unary updates; all coalesced float4.
// Reads left_h/left_v in-place from d_out slots 2/3 and overwrites with margs.
// ---------------------------------------------------------------------------
__global__ __launch_bounds__(256) void combine_kernel(
    const float* __restrict__ hu, const float* __restrict__ vu,
    const float* __restrict__ rh, const float* __restrict__ rv,
    float* __restrict__ o)
{
    const int i = blockIdx.x * 256 + threadIdx.x;   // float4 index, 0..524287
    const float4* hu4 = (const float4*)hu;
    const float4* vu4 = (const float4*)vu;
    const float4* lh4 = (const float4*)(o + 2 * (size_t)NF);
    const float4* lv4 = (const float4*)(o + 3 * (size_t)NF);
    const float4* rh4 = (const float4*)rh;
    const float4* rv4 = (const float4*)rv;
    float4* o0 = (float4*)o;
    float4* o1 = (float4*)(o + (size_t)NF);
    float4* o2 = (float4*)(o + 2 * (size_t)NF);
    float4* o3 = (float4*)(o + 3 * (size_t)NF);

    float4 A = hu4[i], B = vu4[i];
    float4 LH = lh4[i], RH = rh4[i], LV = lv4[i], RV = rv4[i];
    float4 HM, VM, U0, U1;
    const float scl = 1.0f / 256.0f;   // 0.5/W = 0.5/H = 1/256
    float* pa  = (float*)&A;  float* pb  = (float*)&B;
    float* plh = (float*)&LH; float* prh = (float*)&RH;
    float* plv = (float*)&LV; float* prv = (float*)&RV;
    float* phm = (float*)&HM; float* pvm = (float*)&VM;
    float* pu0 = (float*)&U0; float* pu1 = (float*)&U1;
    #pragma unroll
    for (int t = 0; t < 4; ++t) {
        const float hm = plh[t] + prh[t] - pa[t];
        const float vm = plv[t] + prv[t] - pb[t];
        phm[t] = hm;
        pvm[t] = vm;
        pu0[t] = pa[t] - (hm - vm) * scl;
        pu1[t] = pb[t] - (vm - hm) * scl;
    }
    o0[i] = U0; o1[i] = U1; o2[i] = HM; o3[i] = VM;
}

extern "C" void kernel_launch(void* const* d_in, const int* in_sizes, int n_in,
                              void* d_out, int out_size, void* d_ws, size_t ws_size,
                              hipStream_t stream) {
    const float* hu  = (const float*)d_in[0];   // horizontal_unary    [4,32,128,128]
    const float* vu  = (const float*)d_in[1];   // vertical_unary      [4,32,128,128]
    const float* hp  = (const float*)d_in[2];   // horizontal_pairwise [4,32,32,128,127]
    const float* vp  = (const float*)d_in[3];   // vertical_pairwise   [4,32,32,127,128]
    const float* gam = (const float*)d_in[4];   // gamma [1]
    float* out = (float*)d_out;

    float* lh = out + 2 * (size_t)NF;           // left_h  -> slot 2 (becomes h_marg)
    float* lv = out + 3 * (size_t)NF;           // left_v  -> slot 3 (becomes v_marg)
    float* rh = (float*)d_ws;                   // right_h
    float* rv = rh + (size_t)NF;                // right_v

    dp_kernel<<<1152, 256, 0, stream>>>(hu, vu, hp, vp, gam, lh, rh, lv, rv);
    combine_kernel<<<2048, 256, 0, stream>>>(hu, vu, rh, rv, out);
}

// Round 2
// 949.329 us; speedup vs baseline: 1.0084x; 1.0084x over previous
//
#include <hip/hip_runtime.h>

#define NF 2097152   // 4*32*128*128 elements per [B,K,H,W] array

// ---------------------------------------------------------------------------
// DP kernel.
//   blocks 0..127    : vertical chains  (scan over h; w contiguous, streamed,
//                      depth-2 register prefetch pipeline)
//   blocks 128..1151 : horizontal chains (scan over w; LDS-staged k-major,
//                      per-step wave-swizzle LSE merge, 1 barrier/step)
// ---------------------------------------------------------------------------
__global__ __launch_bounds__(256) void dp_kernel(
    const float* __restrict__ hu, const float* __restrict__ vu,
    const float* __restrict__ hp, const float* __restrict__ vp,
    const float* __restrict__ gam,
    float* __restrict__ lh, float* __restrict__ rh,
    float* __restrict__ lv, float* __restrict__ rv)
{
    alignas(16) __shared__ float smem[16512];  // H: pbuf[16][1028]+cc[2][32]; V: cb[2][8][36]
    const float g  = gam[0];
    const float ig = 1.0f / g;
    const int tid = threadIdx.x;
    const int blk = blockIdx.x;

    if (blk < 128) {
        // ----------------- VERTICAL: thread = (state k, chain w) -----------------
        const int dir  = blk & 1;
        const int b    = (blk >> 1) & 3;
        const int rblk = blk >> 3;                 // 0..15
        const int rl   = tid & 7;
        const int k    = tid >> 3;                 // state 0..31
        const int r    = rblk * 8 + rl;            // chain index w
        float* cb = smem;                          // [2][8][36] c-exchange, bank-clean

        // p[b,j,k,hh,w]: j stride 520192, k stride 16256, hh stride 128, w stride 1
        const int sIt   = dir ? 16256  : 520192;   // iterated-state stride
        const int sFix  = dir ? 520192 : 16256;    // this thread's state stride
        const int pbase = b * 16646144 + k * sFix + r;
        const int ubase = (b * 32 + k) * 16384 + r;
        const float* __restrict__ p = vp;
        const float* __restrict__ u = vu;
        float* __restrict__ out = dir ? rv : lv;

        const int pos0 = dir ? 127 : 0;
        const float c0 = u[ubase + pos0 * 128];
        cb[rl * 36 + k] = c0;                      // parity-0 buffer
        out[ubase + pos0 * 128] = c0;

        // pcol(s) = dir ? 127-s : s-1 ;  ucol(s) = dir ? 127-s : s
        float b0[32], b1[32], b2[32];
        float u0, u1, u2 = 0.0f;
        {
            const int i1 = pbase + (dir ? 126 : 0) * 128;
            #pragma unroll
            for (int j = 0; j < 32; ++j) b0[j] = p[i1 + j * sIt];
            u0 = u[ubase + (dir ? 126 : 1) * 128];
            const int i2 = pbase + (dir ? 125 : 1) * 128;
            #pragma unroll
            for (int j = 0; j < 32; ++j) b1[j] = p[i2 + j * sIt];
            u1 = u[ubase + (dir ? 125 : 2) * 128];
        }
        __syncthreads();

#define VSTEP(S, CUR, UC, LD, UL)                                             \
        if ((S) <= 127) {                                                     \
            if ((S) + 2 <= 127) {                                             \
                const int pc = dir ? 125 - (S) : (S) + 1;                     \
                const int ib = pbase + pc * 128;                              \
                _Pragma("unroll")                                             \
                for (int j = 0; j < 32; ++j) LD[j] = p[ib + j * sIt];         \
                UL = u[ubase + (dir ? 125 - (S) : (S) + 2) * 128];            \
            }                                                                 \
            {                                                                 \
                const float* cs = cb + ((((S) + 1) & 1) * 288) + rl * 36;     \
                float c4[32];                                                 \
                _Pragma("unroll")                                             \
                for (int jq = 0; jq < 8; ++jq) {                              \
                    const float4 t = *(const float4*)(cs + jq * 4);           \
                    c4[jq*4+0] = t.x; c4[jq*4+1] = t.y;                       \
                    c4[jq*4+2] = t.z; c4[jq*4+3] = t.w;                       \
                }                                                             \
                float mx = -3.4e38f;                                          \
                _Pragma("unroll")                                             \
                for (int j = 0; j < 32; ++j) {                                \
                    CUR[j] += c4[j]; mx = fmaxf(mx, CUR[j]);                  \
                }                                                             \
                float ss = 0.0f;                                              \
                _Pragma("unroll")                                             \
                for (int j = 0; j < 32; ++j) ss += __expf((CUR[j] - mx) * ig);\
                const float nv = UC + mx + g * __logf(ss);                    \
                out[ubase + (dir ? 127 - (S) : (S)) * 128] = nv;              \
                cb[(((S) & 1) * 288) + rl * 36 + k] = nv;                     \
            }                                                                 \
            __syncthreads();                                                  \
        }

        for (int s = 1; s <= 127; s += 3) {
            VSTEP(s,     b0, u0, b2, u2)
            VSTEP(s + 1, b1, u1, b0, u0)
            VSTEP(s + 2, b2, u2, b1, u1)
        }
#undef VSTEP
    } else {
        // ----------------- HORIZONTAL: one block per chain (b,h,dir) -----------------
        const int hid = blk - 128;                 // 0..1023
        const int dir = hid & 1;
        const int b   = (hid >> 1) & 3;
        const int h   = hid >> 3;                  // 0..127
        float (* __restrict__ pbuf)[1028] = (float(*)[1028])smem;
        float* cc = smem + 16448;                  // [2][32]
        const float* __restrict__ p = hp;
        const float* __restrict__ u = hu;
        float* __restrict__ out = dir ? rh : lh;
        // p[b,j,k,h,l]: jk stride 16256, h stride 127, l stride 1
        const int pb = b * 16646144 + h * 127;
        const int ub = b * 524288 + h * 128;
        const int k  = tid >> 3;                   // state 0..31
        const int jq = tid & 7;                    // j-octant
        const int uk = ub + k * 16384;
        const int pos0 = dir ? 127 : 0;
        if (jq == 0) {
            const float c0 = u[uk + pos0];
            cc[k] = c0;
            out[uk + pos0] = c0;
        }
        int sc = 0;
        float u_nxt = 0.0f;
        for (int ci = 0; ci < 8; ++ci) {
            const int l0 = dir ? 112 - ci * 16 : ci * 16;
            const int nl = (l0 == 112) ? 15 : 16;
            // stage p[:, :, h, l0:l0+nl] -> LDS (k-major per lo; bwd keeps jk order)
            #pragma unroll 8
            for (int i = 0; i < 64; ++i) {
                const int q  = i * 256 + tid;
                const int jk = q >> 4, lo = q & 15;
                if (lo < nl) {
                    const float v = p[pb + jk * 16256 + l0 + lo];
                    const int col = dir ? jk : (((jk & 31) << 5) | (jk >> 5));
                    pbuf[lo][col] = v;
                }
            }
            if (jq == 0) {   // prefetch u for first step of this chunk
                const int lo0  = dir ? nl - 1 : 0;
                u_nxt = u[uk + (dir ? l0 + lo0 : l0 + lo0 + 1)];
            }
            __syncthreads();
            for (int li = 0; li < nl; ++li) {
                const int lo  = dir ? nl - 1 - li : li;
                const int pos = dir ? l0 + lo : l0 + lo + 1;
                const float u_cur = u_nxt;
                if (jq == 0 && li + 1 < nl) {     // prefetch next step's u
                    const int lo2 = dir ? nl - 2 - li : li + 1;
                    u_nxt = u[uk + (dir ? l0 + lo2 : l0 + lo2 + 1)];
                }
                const float* cs = cc + ((sc & 1) << 5);
                const float4 pq = *(const float4*)&pbuf[lo][k * 32 + jq * 4];
                const float4 cq = *(const float4*)(cs + jq * 4);
                const float v0 = pq.x + cq.x, v1 = pq.y + cq.y;
                const float v2 = pq.z + cq.z, v3 = pq.w + cq.w;
                float m = fmaxf(fmaxf(v0, v1), fmaxf(v2, v3));
                float s = __expf((v0 - m) * ig) + __expf((v1 - m) * ig)
                        + __expf((v2 - m) * ig) + __expf((v3 - m) * ig);
                #pragma unroll
                for (int d = 1; d <= 4; d <<= 1) {   // merge 8 j-octants in-wave
                    const float mo = __shfl_xor(m, d, 64);
                    const float so = __shfl_xor(s, d, 64);
                    const float mn = fmaxf(m, mo);
                    s = s * __expf((m - mn) * ig) + so * __expf((mo - mn) * ig);
                    m = mn;
                }
                if (jq == 0) {
                    const float nv = u_cur + m + g * __logf(s);
                    out[uk + pos] = nv;
                    cc[(((sc + 1) & 1) << 5) + k] = nv;
                }
                __syncthreads();
                ++sc;
            }
        }
    }
}

// ---------------------------------------------------------------------------
// Combine: marg = left + right - u; unary updates; all coalesced float4.
// ---------------------------------------------------------------------------
__global__ __launch_bounds__(256) void combine_kernel(
    const float* __restrict__ hu, const float* __restrict__ vu,
    const float* __restrict__ rh, const float* __restrict__ rv,
    float* __restrict__ o)
{
    const int i = blockIdx.x * 256 + threadIdx.x;   // float4 index, 0..524287
    const float4* hu4 = (const float4*)hu;
    const float4* vu4 = (const float4*)vu;
    const float4* lh4 = (const float4*)(o + 2 * (size_t)NF);
    const float4* lv4 = (const float4*)(o + 3 * (size_t)NF);
    const float4* rh4 = (const float4*)rh;
    const float4* rv4 = (const float4*)rv;
    float4* o0 = (float4*)o;
    float4* o1 = (float4*)(o + (size_t)NF);
    float4* o2 = (float4*)(o + 2 * (size_t)NF);
    float4* o3 = (float4*)(o + 3 * (size_t)NF);

    float4 A = hu4[i], B = vu4[i];
    float4 LH = lh4[i], RH = rh4[i], LV = lv4[i], RV = rv4[i];
    float4 HM, VM, U0, U1;
    const float scl = 1.0f / 256.0f;   // 0.5/W = 0.5/H
    float* pa  = (float*)&A;  float* pb  = (float*)&B;
    float* plh = (float*)&LH; float* prh = (float*)&RH;
    float* plv = (float*)&LV; float* prv = (float*)&RV;
    float* phm = (float*)&HM; float* pvm = (float*)&VM;
    float* pu0 = (float*)&U0; float* pu1 = (float*)&U1;
    #pragma unroll
    for (int t = 0; t < 4; ++t) {
        const float hm = plh[t] + prh[t] - pa[t];
        const float vm = plv[t] + prv[t] - pb[t];
        phm[t] = hm;
        pvm[t] = vm;
        pu0[t] = pa[t] - (hm - vm) * scl;
        pu1[t] = pb[t] - (vm - hm) * scl;
    }
    o0[i] = U0; o1[i] = U1; o2[i] = HM; o3[i] = VM;
}

extern "C" void kernel_launch(void* const* d_in, const int* in_sizes, int n_in,
                              void* d_out, int out_size, void* d_ws, size_t ws_size,
                              hipStream_t stream) {
    const float* hu  = (const float*)d_in[0];   // horizontal_unary    [4,32,128,128]
    const float* vu  = (const float*)d_in[1];   // vertical_unary      [4,32,128,128]
    const float* hp  = (const float*)d_in[2];   // horizontal_pairwise [4,32,32,128,127]
    const float* vp  = (const float*)d_in[3];   // vertical_pairwise   [4,32,32,127,128]
    const float* gam = (const float*)d_in[4];   // gamma [1]
    float* out = (float*)d_out;

    float* lh = out + 2 * (size_t)NF;           // left_h  -> slot 2 (becomes h_marg)
    float* lv = out + 3 * (size_t)NF;           // left_v  -> slot 3 (becomes v_marg)
    float* rh = (float*)d_ws;                   // right_h
    float* rv = rh + (size_t)NF;                // right_v

    dp_kernel<<<1152, 256, 0, stream>>>(hu, vu, hp, vp, gam, lh, rh, lv, rv);
    combine_kernel<<<2048, 256, 0, stream>>>(hu, vu, rh, rv, out);
}